// Round 9
// baseline (172.530 us; speedup 1.0000x reference)
//
#include <hip/hip_runtime.h>
#include <hip/hip_bf16.h>

typedef __attribute__((ext_vector_type(4))) float f32x4;
typedef __attribute__((ext_vector_type(8))) short s16x8;
typedef __attribute__((ext_vector_type(8))) unsigned short u16x8;

#define DEVFN static __device__ __forceinline__

DEVFN unsigned short f2bf(float f) {
  union { float f; unsigned int u; } v; v.f = f;
  unsigned int u = v.u;
  u += 0x7fffu + ((u >> 16) & 1u);   // RNE
  return (unsigned short)(u >> 16);
}

DEVFN unsigned int cvt_pk(float a, float b) {
  __hip_bfloat162 h = __float22bfloat162_rn(make_float2(a, b));
  union { __hip_bfloat162 h; unsigned int u; } v; v.h = h; return v.u;
}

DEVFN void gl_lds16(const void* g, void* l) {
  __builtin_amdgcn_global_load_lds((__attribute__((address_space(1))) void*)g,
                                   (__attribute__((address_space(3))) void*)l, 16, 0, 0);
}

#define SB() __builtin_amdgcn_sched_barrier(0)

// ws layout (bytes)
#define DG_OFF 0
#define DB_OFF 2048
#define UG_OFF 4096
#define UB_OFF 12288
#define F1_BYTE 81920        // FRAG1: [16 kc][2 kf][8 wn][2 nf][64 lane]x16B = 512 KB
#define F2_BYTE 606208       // FRAG2: [8 nt][4 kc][2 kf][8 nfq][64 lane]x16B = 512 KB

// ---------- prep: FRAG1 (0..31) + FRAG2 (32..95) + coef (96..255) ----------
__global__ void prep_kernel(const float* __restrict__ cond,
                            const float* __restrict__ dgm, const float* __restrict__ dbt,
                            const float* __restrict__ ugm, const float* __restrict__ ubt,
                            const float* __restrict__ Wd, const float* __restrict__ Wu,
                            char* __restrict__ ws) {
  __shared__ float lc[4096];
  __shared__ float red[2048];
  const int t = threadIdx.x;
  const int lane = t & 63, lr = lane & 15, lq = lane >> 4;

  if (blockIdx.x < 32) {
    // FRAG1 group (kc,kf,wn,nf): lane 16B = Wd[kc*64+(kf*4+lq)*8+e][wn*32+nf*16+lr]
    const int kc = blockIdx.x >> 1, kf = blockIdx.x & 1;
    const int grp0 = t >> 6;
#pragma unroll
    for (int it = 0; it < 4; ++it) {
      int grp = grp0 + it * 4;             // wn*2+nf
      int n = (grp >> 1) * 32 + (grp & 1) * 16 + lr;
      int k0 = kc * 64 + (kf * 4 + lq) * 8;
      u16x8 v;
#pragma unroll
      for (int e = 0; e < 8; ++e) v[e] = f2bf(Wd[(size_t)(k0 + e) * 256 + n]);
      *(u16x8*)(ws + F1_BYTE + ((size_t)((kc * 2 + kf) * 16 + grp)) * 1024 + lane * 16) = v;
    }
    return;
  }
  if (blockIdx.x < 96) {
    // FRAG2 group (nt,kc,kf,nfq): lane 16B = Wu[kc*64+(kf*4+lq)*8+e][nt*128+nfq*16+lr]
    const int id = blockIdx.x - 32;
    const int nt = id >> 3, kc = (id >> 1) & 3, kf = id & 1;
    const int grp0 = t >> 6;
#pragma unroll
    for (int it = 0; it < 2; ++it) {
      int nfq = grp0 + it * 4;
      int n = nt * 128 + nfq * 16 + lr;
      int k0 = kc * 64 + (kf * 4 + lq) * 8;
      u16x8 v;
#pragma unroll
      for (int e = 0; e < 8; ++e) v[e] = f2bf(Wu[(size_t)(k0 + e) * 1024 + n]);
      *(u16x8*)(ws + F2_BYTE + ((size_t)(((nt * 4 + kc) * 2 + kf) * 8 + nfq)) * 1024 + lane * 16) = v;
    }
    return;
  }

  // ----- coefficient GEMMs -----
  float* coef = (float*)ws;
#pragma unroll
  for (int i = 0; i < 16; ++i) lc[t + i * 256] = cond[t + i * 256];
  __syncthreads();
  const int bid2 = blockIdx.x - 96;
  const int col = bid2 * 16 + (t & 15);
  const int ks = t >> 4;
  const float* src; int ncol, cl;
  if (col < 256)       { src = dgm; ncol = 256;  cl = col; }
  else if (col < 512)  { src = dbt; ncol = 256;  cl = col - 256; }
  else if (col < 1536) { src = ugm; ncol = 1024; cl = col - 512; }
  else                 { src = ubt; ncol = 1024; cl = col - 1536; }
  float acc[8] = {};
  for (int k = ks * 32; k < ks * 32 + 32; ++k) {
    float g = src[(size_t)k * ncol + cl];
#pragma unroll
    for (int b = 0; b < 8; ++b) acc[b] = fmaf(lc[b * 512 + k], g, acc[b]);
  }
#pragma unroll
  for (int b = 0; b < 8; ++b) red[(ks * 16 + (t & 15)) * 8 + b] = acc[b];
  __syncthreads();
  if (t < 128) {
    int c = t >> 3, b = t & 7;
    float s = 0.f;
#pragma unroll
    for (int k2 = 0; k2 < 16; ++k2) s += red[(k2 * 16 + c) * 8 + b];
    int colg = bid2 * 16 + c;
    float* dst; int ncol2, cl2;
    if (colg < 256)       { dst = coef + DG_OFF; ncol2 = 256;  cl2 = colg; }
    else if (colg < 512)  { dst = coef + DB_OFF; ncol2 = 256;  cl2 = colg - 256; }
    else if (colg < 1536) { dst = coef + UG_OFF; ncol2 = 1024; cl2 = colg - 512; }
    else                  { dst = coef + UB_OFF; ncol2 = 1024; cl2 = colg - 1536; }
    dst[b * ncol2 + cl2] = s;
  }
}

// ---------- fused kernel: 512 blocks x 512 threads, 2 blocks/CU ----------
// BM=64. LDS 80 KiB: act[4kc][64r][64k]bf16 @0 (32K) | X f32 3-buf @32K (3x16K)
// Phase 1: X dbuf via gl_lds (round-6 swizzle), W1 frags direct from L2.
// Phase 2: barrier-free; wave wn owns cols wn*128..+127; W2 frags from L2.
__global__ __launch_bounds__(512, 4)
void fused_kernel(const float* __restrict__ X, const char* __restrict__ ws,
                  float* __restrict__ out) {
  __shared__ char lds[81920];
  const int tid = threadIdx.x;
  const int lane = tid & 63, lr = lane & 15, lq = lane >> 4;
  const int wn = tid >> 6;

  const int raw = blockIdx.x;
  const int m = (raw & 7) * 64 + (raw >> 3);   // XCD-chunked, 512 % 8 == 0
  const int row0 = m << 6;
  const int b = m >> 6;

  const float* coef = (const float*)ws;
  const char* frag1 = ws + F1_BYTE;
  const char* frag2 = ws + F2_BYTE;

  // ===== phase 1: X @ Wd, BK=64, 16 steps =====
  // X staging: thread covers (row tid>>4, granule tid&15) and (row+32, same granule)
  const int s0r = tid >> 4, s0g = tid & 15;
  const float* xs0 = X + (size_t)(row0 + s0r) * 1024 + ((s0g ^ (s0r & 15)) << 2);

  int aoff[4][2][2];
#pragma unroll
  for (int mf = 0; mf < 4; ++mf)
#pragma unroll
    for (int kf = 0; kf < 2; ++kf) {
      int r = mf * 16 + lr;
      int g0 = kf * 8 + lq * 2;
      aoff[mf][kf][0] = r * 256 + ((g0 ^ (r & 15)) << 4);
      aoff[mf][kf][1] = r * 256 + (((g0 + 1) ^ (r & 15)) << 4);
    }

  f32x4 acc1[4][2] = {};
  float hacc[4] = {};

#define XB(i) (lds + 32768 + (i) * 16384)
#define STAGE_X3(t)                                                              \
  { char* xb = XB((t) % 3);                                                      \
    gl_lds16(xs0 + (size_t)(t) * 64, xb + tid * 16);                             \
    gl_lds16(xs0 + 32 * 1024 + (size_t)(t) * 64, xb + 8192 + tid * 16); }

  STAGE_X3(0); STAGE_X3(1); STAGE_X3(2);
  asm volatile("s_waitcnt vmcnt(4)" ::: "memory");
  SB(); __builtin_amdgcn_s_barrier(); SB();

  for (int t = 0; t < 16; ++t) {
    const char* Xc = XB(t % 3);
    // B-fragments: coalesced 1KB reads from L2-resident FRAG1
    s16x8 bfr[2][2];
#pragma unroll
    for (int kf = 0; kf < 2; ++kf)
#pragma unroll
      for (int nf = 0; nf < 2; ++nf)
        bfr[kf][nf] = *(const s16x8*)(frag1 +
            ((size_t)((t * 2 + kf) * 16 + wn * 2 + nf)) * 1024 + lane * 16);
#pragma unroll
    for (int kf = 0; kf < 2; ++kf) {
      s16x8 afr[4];
#pragma unroll
      for (int mf = 0; mf < 4; ++mf) {
        f32x4 fa0 = *(const f32x4*)(Xc + aoff[mf][kf][0]);
        f32x4 fa1 = *(const f32x4*)(Xc + aoff[mf][kf][1]);
        if (wn == 0)
          hacc[mf] += fa0[0] + fa0[1] + fa0[2] + fa0[3] + fa1[0] + fa1[1] + fa1[2] + fa1[3];
        union { unsigned int u[4]; s16x8 s; } cv;
        cv.u[0] = cvt_pk(fa0[0], fa0[1]); cv.u[1] = cvt_pk(fa0[2], fa0[3]);
        cv.u[2] = cvt_pk(fa1[0], fa1[1]); cv.u[3] = cvt_pk(fa1[2], fa1[3]);
        afr[mf] = cv.s;
      }
#pragma unroll
      for (int mf = 0; mf < 4; ++mf)
#pragma unroll
        for (int nf = 0; nf < 2; ++nf)
          acc1[mf][nf] = __builtin_amdgcn_mfma_f32_16x16x32_bf16(afr[mf], bfr[kf][nf], acc1[mf][nf], 0, 0, 0);
    }
    asm volatile("s_waitcnt lgkmcnt(0)" ::: "memory");
    SB(); __builtin_amdgcn_s_barrier(); SB();
    if (t < 13) STAGE_X3(t + 3);
    if (t < 15) {
      if (t < 13)      asm volatile("s_waitcnt vmcnt(4)" ::: "memory");
      else if (t < 14) asm volatile("s_waitcnt vmcnt(2)" ::: "memory");
      else             asm volatile("s_waitcnt vmcnt(0)" ::: "memory");
      SB(); __builtin_amdgcn_s_barrier(); SB();
    }
  }

  // ===== phase-1 epilogue: hsum, modulate+relu -> act LDS, asum =====
  float* hsumb = (float*)(lds + 32768);        // 64 f32 (X bufs now free)
  float* asp   = (float*)(lds + 33024);        // [8][64] f32
  if (wn == 0) {
#pragma unroll
    for (int mf = 0; mf < 4; ++mf) {
      float s = hacc[mf];
      s += __shfl_xor(s, 16); s += __shfl_xor(s, 32);
      if (lq == 0) hsumb[mf * 16 + lr] = s;
    }
  }
  __syncthreads();

  float dgv[2], dbv[2];
#pragma unroll
  for (int nf = 0; nf < 2; ++nf) {
    int h = wn * 32 + nf * 16 + lr;
    dgv[nf] = coef[DG_OFF + b * 256 + h];
    dbv[nf] = coef[DB_OFF + b * 256 + h];
  }

  float asacc[4][4] = {};
  {
    char* kcb = lds + (wn >> 1) * 8192 + (lr & 7) * 2;
#pragma unroll
    for (int nf = 0; nf < 2; ++nf) {
      int gk = (wn & 1) * 4 + nf * 2 + (lr >> 3);
      float dg_ = dgv[nf], db_ = dbv[nf];
#pragma unroll
      for (int mf = 0; mf < 4; ++mf) {
#pragma unroll
        for (int j = 0; j < 4; ++j) {
          int r = mf * 16 + lq * 4 + j;
          float v = acc1[mf][nf][j] * dg_ + db_ * hsumb[r];
          v = fmaxf(v, 0.f);
          asacc[mf][j] += v;
          *(unsigned short*)(kcb + r * 128 + ((gk ^ (r & 7)) << 4)) = f2bf(v);
        }
      }
    }
  }
#pragma unroll
  for (int mf = 0; mf < 4; ++mf)
#pragma unroll
    for (int j = 0; j < 4; ++j) {
      float s = asacc[mf][j];
      s += __shfl_xor(s, 1); s += __shfl_xor(s, 2); s += __shfl_xor(s, 4); s += __shfl_xor(s, 8);
      if (lr == 0) asp[wn * 64 + mf * 16 + lq * 4 + j] = s;
    }
  __syncthreads();

  // ===== phase 2: act @ Wu — barrier-free, wave wn owns cols wn*128..+127 =====
  float asv[4][4];
#pragma unroll
  for (int mf = 0; mf < 4; ++mf)
#pragma unroll
    for (int j = 0; j < 4; ++j) {
      int r = mf * 16 + lq * 4 + j;
      float s = 0.f;
#pragma unroll
      for (int w = 0; w < 8; ++w) s += asp[w * 64 + r];
      asv[mf][j] = s;
    }
  float ugA[4][2], ubA[4][2];
#pragma unroll
  for (int p = 0; p < 4; ++p)
#pragma unroll
    for (int nf = 0; nf < 2; ++nf) {
      int d = wn * 128 + p * 32 + nf * 16 + lr;
      ugA[p][nf] = coef[UG_OFF + b * 1024 + d];
      ubA[p][nf] = coef[UB_OFF + b * 1024 + d];
    }

  int a2off[4][2];
#pragma unroll
  for (int mf = 0; mf < 4; ++mf)
#pragma unroll
    for (int kf = 0; kf < 2; ++kf) {
      int r = mf * 16 + lr;
      a2off[mf][kf] = r * 128 + (((kf * 4 + lq) ^ (r & 7)) << 4);
    }

#pragma unroll
  for (int p = 0; p < 4; ++p) {
    f32x4 acc2[4][2] = {};
#pragma unroll
    for (int kc = 0; kc < 4; ++kc) {
#pragma unroll
      for (int kf = 0; kf < 2; ++kf) {
        s16x8 a2[4], bb[2];
#pragma unroll
        for (int mf = 0; mf < 4; ++mf)
          a2[mf] = *(const s16x8*)(lds + kc * 8192 + a2off[mf][kf]);
#pragma unroll
        for (int nf = 0; nf < 2; ++nf)
          bb[nf] = *(const s16x8*)(frag2 +
              ((size_t)(((wn * 4 + kc) * 2 + kf) * 8 + p * 2 + nf)) * 1024 + lane * 16);
#pragma unroll
        for (int mf = 0; mf < 4; ++mf)
#pragma unroll
          for (int nf = 0; nf < 2; ++nf)
            acc2[mf][nf] = __builtin_amdgcn_mfma_f32_16x16x32_bf16(a2[mf], bb[nf], acc2[mf][nf], 0, 0, 0);
      }
    }
    // epilogue for this 32-col chunk: modulation + asum + residual
#pragma unroll
    for (int mf = 0; mf < 4; ++mf)
#pragma unroll
      for (int j = 0; j < 4; ++j) {
        int r = mf * 16 + lq * 4 + j;
        size_t gbase = (size_t)(row0 + r) * 1024 + wn * 128 + p * 32;
#pragma unroll
        for (int nf = 0; nf < 2; ++nf) {
          size_t gi = gbase + nf * 16 + lr;
          out[gi] = acc2[mf][nf][j] * ugA[p][nf] + ubA[p][nf] * asv[mf][j] + X[gi];
        }
      }
  }
}

extern "C" void kernel_launch(void* const* d_in, const int* in_sizes, int n_in,
                              void* d_out, int out_size, void* d_ws, size_t ws_size,
                              hipStream_t stream) {
  const float* hidden       = (const float*)d_in[0];
  const float* conditions   = (const float*)d_in[1];
  const float* down_project = (const float*)d_in[2];
  const float* down_gamma   = (const float*)d_in[3];
  const float* down_beta    = (const float*)d_in[4];
  const float* up_project   = (const float*)d_in[5];
  const float* up_gamma     = (const float*)d_in[6];
  const float* up_beta      = (const float*)d_in[7];
  float* out = (float*)d_out;
  char* ws = (char*)d_ws;

  prep_kernel<<<256, 256, 0, stream>>>(conditions, down_gamma, down_beta, up_gamma, up_beta,
                                       down_project, up_project, ws);
  fused_kernel<<<512, 512, 0, stream>>>(hidden, ws, out);
}

// Round 10
// 94.249 us; speedup vs baseline: 1.8306x; 1.8306x over previous
//
#include <hip/hip_runtime.h>
#include <hip/hip_bf16.h>

typedef __attribute__((ext_vector_type(4))) float f32x4;
typedef __attribute__((ext_vector_type(8))) short s16x8;
typedef __attribute__((ext_vector_type(8))) unsigned short u16x8;
typedef __attribute__((ext_vector_type(4))) unsigned int u32x4;

#define DEVFN static __device__ __forceinline__

DEVFN unsigned short f2bf(float f) {
  union { float f; unsigned int u; } v; v.f = f;
  unsigned int u = v.u;
  u += 0x7fffu + ((u >> 16) & 1u);   // RNE
  return (unsigned short)(u >> 16);
}

DEVFN unsigned int cvt_pk(float a, float b) {
  __hip_bfloat162 h = __float22bfloat162_rn(make_float2(a, b));
  union { __hip_bfloat162 h; unsigned int u; } v; v.h = h; return v.u;
}

DEVFN void gl_lds16(const void* g, void* l) {
  __builtin_amdgcn_global_load_lds((__attribute__((address_space(1))) void*)g,
                                   (__attribute__((address_space(3))) void*)l, 16, 0, 0);
}

// pinned scalar async load (cannot be sunk by the scheduler)
DEVFN float async_ldf(const float* p) {
  float v;
  asm volatile("global_load_dword %0, %1, off"
               : "=v"(v)
               : "v"((unsigned long long)(uintptr_t)p)
               : "memory");
  return v;
}

#define SB() __builtin_amdgcn_sched_barrier(0)
#define VMW(n) asm volatile("s_waitcnt vmcnt(" #n ")" ::: "memory")

// ws layout (bytes)
#define DG_OFF 0
#define DB_OFF 2048
#define UG_OFF 4096
#define UB_OFF 12288
#define W1_BYTE 81920        // [16 kc][2 ntile][128 n][64 k] bf16 swizzled (512 KB)
#define W2_BYTE 606208       // [8 nt][4 kc][128 n][64 k] bf16 swizzled    (512 KB)

// ---------- merged prep: wimg (blocks 0..63) + coef (blocks 64..223) ----------
__global__ void prep_kernel(const float* __restrict__ cond,
                            const float* __restrict__ dgm, const float* __restrict__ dbt,
                            const float* __restrict__ ugm, const float* __restrict__ ubt,
                            const float* __restrict__ Wd, const float* __restrict__ Wu,
                            char* __restrict__ ws) {
  __shared__ float lc[4096];
  __shared__ float red[2048];
  const int t = threadIdx.x;

  if (blockIdx.x < 64) {
    const int bid = blockIdx.x;
    const float* src; char* dst; int C, ntile, kc;
    if (bid < 32) { src = Wd; C = 256;  ntile = bid >> 4; kc = bid & 15;
                    dst = ws + W1_BYTE + (size_t)(kc * 2 + ntile) * 16384; }
    else { int b2 = bid - 32; src = Wu; C = 1024; ntile = b2 >> 2; kc = b2 & 3;
           dst = ws + W2_BYTE + (size_t)(ntile * 4 + kc) * 16384; }
    const int n = t >> 1, kh = t & 1;
    const float* sp = src + (size_t)(kc * 64 + kh * 32) * C + ntile * 128 + n;
    unsigned short tmp[32];
#pragma unroll
    for (int kk = 0; kk < 32; ++kk) tmp[kk] = f2bf(sp[(size_t)kk * C]);
    char* drow = dst + n * 128;
#pragma unroll
    for (int gi = 0; gi < 4; ++gi) {
      u16x8 v;
#pragma unroll
      for (int e = 0; e < 8; ++e) v[e] = tmp[gi * 8 + e];
      int g = kh * 4 + gi;
      *(u16x8*)(drow + ((g ^ (n & 7)) << 4)) = v;
    }
    return;
  }

  float* coef = (float*)ws;
#pragma unroll
  for (int i = 0; i < 16; ++i) lc[t + i * 256] = cond[t + i * 256];
  __syncthreads();
  const int bid2 = blockIdx.x - 64;
  const int col = bid2 * 16 + (t & 15);
  const int ks = t >> 4;
  const float* src; int ncol, cl;
  if (col < 256)       { src = dgm; ncol = 256;  cl = col; }
  else if (col < 512)  { src = dbt; ncol = 256;  cl = col - 256; }
  else if (col < 1536) { src = ugm; ncol = 1024; cl = col - 512; }
  else                 { src = ubt; ncol = 1024; cl = col - 1536; }
  float acc[8] = {};
  for (int k = ks * 32; k < ks * 32 + 32; ++k) {
    float g = src[(size_t)k * ncol + cl];
#pragma unroll
    for (int b = 0; b < 8; ++b) acc[b] = fmaf(lc[b * 512 + k], g, acc[b]);
  }
#pragma unroll
  for (int b = 0; b < 8; ++b) red[(ks * 16 + (t & 15)) * 8 + b] = acc[b];
  __syncthreads();
  if (t < 128) {
    int c = t >> 3, b = t & 7;
    float s = 0.f;
#pragma unroll
    for (int k2 = 0; k2 < 16; ++k2) s += red[(k2 * 16 + c) * 8 + b];
    int colg = bid2 * 16 + c;
    float* dst; int ncol2, cl2;
    if (colg < 256)       { dst = coef + DG_OFF; ncol2 = 256;  cl2 = colg; }
    else if (colg < 512)  { dst = coef + DB_OFF; ncol2 = 256;  cl2 = colg - 256; }
    else if (colg < 1536) { dst = coef + UG_OFF; ncol2 = 1024; cl2 = colg - 512; }
    else                  { dst = coef + UB_OFF; ncol2 = 1024; cl2 = colg - 1536; }
    dst[b * ncol2 + cl2] = s;
  }
}

// ---------- fused kernel: act stays in LDS (round-6 structure) ----------
// 256 blocks x 512 threads (8 waves, 2m x 4n), 128 rows per block, 1 block/CU.
// LDS 160 KiB: act[4 kc][128 r][64 k] bf16 @0 (64K) | X dbuf / W2 quad @64K | W1 @128K
__global__ __launch_bounds__(512, 1)
void fused_kernel(const float* __restrict__ X, char* __restrict__ ws,
                  float* __restrict__ out) {
  __shared__ char lds[163840];
  const int tid = threadIdx.x;
  const int lane = tid & 63, lr = lane & 15, lq = lane >> 4;
  const int wave = tid >> 6;
  const int wm = wave >> 2, wn = wave & 3;   // 2m x 4n

  const int m0 = blockIdx.x;
  const int row0 = m0 << 7;
  const int b = m0 >> 5;

  const float* coef = (const float*)ws;
  const char* w1 = ws + W1_BYTE;
  const char* w2 = ws + W2_BYTE;

  // ===== phase 1: X @ Wd =====
  const int srow = tid >> 4, sg = tid & 15;
  const float* xsrc = X + (size_t)(row0 + srow) * 1024 + ((sg ^ (srow & 15)) << 2);

  int aoff[4][2][2], boff[4][2];
#pragma unroll
  for (int mf = 0; mf < 4; ++mf)
#pragma unroll
    for (int kf = 0; kf < 2; ++kf) {
      int r = wm * 64 + mf * 16 + lr;
      int g0 = kf * 8 + lq * 2;
      aoff[mf][kf][0] = r * 256 + ((g0 ^ (r & 15)) << 4);
      aoff[mf][kf][1] = r * 256 + (((g0 + 1) ^ (r & 15)) << 4);
    }
#pragma unroll
  for (int nf = 0; nf < 4; ++nf)
#pragma unroll
    for (int kf = 0; kf < 2; ++kf) {
      int n = wn * 64 + nf * 16 + lr;
      boff[nf][kf] = 131072 + (n >> 7) * 16384 + (n & 127) * 128 +
                     (((kf * 4 + lq) ^ (n & 7)) << 4);
    }

  f32x4 acc1[4][4] = {};
  float hacc[4] = {};

#define STAGE_X(t)                                                               \
  { char* xb = lds + 65536 + ((t) & 1) * 32768;                                  \
    _Pragma("unroll")                                                            \
    for (int i = 0; i < 4; ++i)                                                  \
      gl_lds16(xsrc + (size_t)((t) * 64) + (size_t)(i * 32) * 1024,              \
               xb + i * 8192 + tid * 16); }
#define STAGE_W1(t)                                                              \
  { _Pragma("unroll")                                                            \
    for (int i = 0; i < 4; ++i)                                                  \
      gl_lds16(w1 + (size_t)(t) * 32768 + i * 8192 + tid * 16,                   \
               lds + 131072 + i * 8192 + tid * 16); }

  STAGE_X(0); STAGE_X(1); STAGE_W1(0);
  asm volatile("s_waitcnt vmcnt(0)" ::: "memory");
  SB(); __builtin_amdgcn_s_barrier(); SB();

  for (int t = 0; t < 16; ++t) {
    const char* Xc = lds + 65536 + (t & 1) * 32768;
#pragma unroll
    for (int kf = 0; kf < 2; ++kf) {
      s16x8 afr[4], bfr[4];
#pragma unroll
      for (int mf = 0; mf < 4; ++mf) {
        f32x4 fa0 = *(const f32x4*)(Xc + aoff[mf][kf][0]);
        f32x4 fa1 = *(const f32x4*)(Xc + aoff[mf][kf][1]);
        if (wn == 0)
          hacc[mf] += fa0[0] + fa0[1] + fa0[2] + fa0[3] + fa1[0] + fa1[1] + fa1[2] + fa1[3];
        u32x4 p;
        p[0] = cvt_pk(fa0[0], fa0[1]); p[1] = cvt_pk(fa0[2], fa0[3]);
        p[2] = cvt_pk(fa1[0], fa1[1]); p[3] = cvt_pk(fa1[2], fa1[3]);
        union { u32x4 u; s16x8 s; } cv; cv.u = p; afr[mf] = cv.s;
      }
#pragma unroll
      for (int nf = 0; nf < 4; ++nf) bfr[nf] = *(const s16x8*)(lds + boff[nf][kf]);
#pragma unroll
      for (int mf = 0; mf < 4; ++mf)
#pragma unroll
        for (int nf = 0; nf < 4; ++nf)
          acc1[mf][nf] = __builtin_amdgcn_mfma_f32_16x16x32_bf16(afr[mf], bfr[nf], acc1[mf][nf], 0, 0, 0);
    }
    asm volatile("s_waitcnt lgkmcnt(0)" ::: "memory");
    SB(); __builtin_amdgcn_s_barrier(); SB();
    if (t < 15) {
      STAGE_W1(t + 1);
      if (t + 2 < 16) { STAGE_X(t + 2); asm volatile("s_waitcnt vmcnt(4)" ::: "memory"); }
      else            { asm volatile("s_waitcnt vmcnt(0)" ::: "memory"); }
      SB(); __builtin_amdgcn_s_barrier(); SB();
    }
  }

  // ===== phase-1 epilogue: hsum, modulate+relu -> act LDS, asum =====
  float* hsumb = (float*)(lds + 65536);           // 128 f32
  float* asp   = (float*)(lds + 65536 + 512);     // [4][128] f32
  if (wn == 0) {
#pragma unroll
    for (int mf = 0; mf < 4; ++mf) {
      float s = hacc[mf];
      s += __shfl_xor(s, 16); s += __shfl_xor(s, 32);
      if (lq == 0) hsumb[wm * 64 + mf * 16 + lr] = s;
    }
  }
  __syncthreads();

  float dgv[4], dbv[4];
#pragma unroll
  for (int nf = 0; nf < 4; ++nf) {
    int h = wn * 64 + nf * 16 + lr;
    dgv[nf] = coef[DG_OFF + b * 256 + h];
    dbv[nf] = coef[DB_OFF + b * 256 + h];
  }

  float asacc[4][4] = {};
#pragma unroll
  for (int nf = 0; nf < 4; ++nf) {
    int g = nf * 2 + (lr >> 3);
    char* nbase = lds + wn * 16384 + (lr & 7) * 2;   // act chunk kc = wn
    float dg_ = dgv[nf], db_ = dbv[nf];
#pragma unroll
    for (int mf = 0; mf < 4; ++mf) {
      int rb = wm * 64 + mf * 16 + lq * 4;
#pragma unroll
      for (int j = 0; j < 4; ++j) {
        int r = rb + j;
        float v = acc1[mf][nf][j] * dg_ + db_ * hsumb[r];
        v = fmaxf(v, 0.f);
        asacc[mf][j] += v;
        *(unsigned short*)(nbase + r * 128 + ((g ^ (r & 7)) << 4)) = f2bf(v);
      }
    }
  }
#pragma unroll
  for (int mf = 0; mf < 4; ++mf)
#pragma unroll
    for (int j = 0; j < 4; ++j) {
      float s = asacc[mf][j];
      s += __shfl_xor(s, 1); s += __shfl_xor(s, 2); s += __shfl_xor(s, 4); s += __shfl_xor(s, 8);
      if (lr == 0) asp[wn * 128 + wm * 64 + mf * 16 + lq * 4 + j] = s;
    }
  __syncthreads();

  // ===== phase-2 preloads (asp/hsumb consumed, then their LDS is reused) =====
  float asv[4][4];
#pragma unroll
  for (int mf = 0; mf < 4; ++mf)
#pragma unroll
    for (int j = 0; j < 4; ++j) {
      int r = wm * 64 + mf * 16 + lq * 4 + j;
      asv[mf][j] = asp[r] + asp[128 + r] + asp[256 + r] + asp[384 + r];
    }
  float ugA[8][2], ubA[8][2];
#pragma unroll
  for (int nt = 0; nt < 8; ++nt)
#pragma unroll
    for (int nf = 0; nf < 2; ++nf) {
      int d = nt * 128 + wn * 32 + nf * 16 + lr;
      ugA[nt][nf] = coef[UG_OFF + b * 1024 + d];
      ubA[nt][nf] = coef[UB_OFF + b * 1024 + d];
    }
  __syncthreads();   // asp reads complete before W2 staging overwrites 65536..

  int a2off[4][2], b2off[2][2];
#pragma unroll
  for (int mf = 0; mf < 4; ++mf)
#pragma unroll
    for (int kf = 0; kf < 2; ++kf) {
      int r = wm * 64 + mf * 16 + lr;
      a2off[mf][kf] = r * 128 + (((kf * 4 + lq) ^ (r & 7)) << 4);
    }
#pragma unroll
  for (int nf = 0; nf < 2; ++nf)
#pragma unroll
    for (int kf = 0; kf < 2; ++kf) {
      int nl = wn * 32 + nf * 16 + lr;
      b2off[nf][kf] = nl * 128 + (((kf * 4 + lq) ^ (nl & 7)) << 4);
    }

  // W2 quad-buffer at 65536 + (s&3)*16384
#define STAGE_W2(s)                                                              \
  { _Pragma("unroll")                                                            \
    for (int i = 0; i < 2; ++i)                                                  \
      gl_lds16(w2 + (size_t)(s) * 16384 + i * 8192 + tid * 16,                   \
               lds + 65536 + ((s) & 3) * 16384 + i * 8192 + tid * 16); }

  STAGE_W2(0); STAGE_W2(1); STAGE_W2(2); STAGE_W2(3);
  VMW(6);                     // retire W2(0); W2(1..3) stay in flight
  SB(); __builtin_amdgcn_s_barrier(); SB();

  // ===== phase 2: act @ Wu, fully unrolled; 4-deep W2, async residual X =====
#pragma unroll
  for (int nt = 0; nt < 8; ++nt) {
    f32x4 acc2[4][2] = {};
    float xres[4][4][2];
#pragma unroll
    for (int kc = 0; kc < 4; ++kc) {
      const int s = nt * 4 + kc;
      const char* Wb = lds + 65536 + (s & 3) * 16384;
#pragma unroll
      for (int kf = 0; kf < 2; ++kf) {
        s16x8 a2[4], bb[2];
#pragma unroll
        for (int mf = 0; mf < 4; ++mf)
          a2[mf] = *(const s16x8*)(lds + kc * 16384 + a2off[mf][kf]);
#pragma unroll
        for (int nf = 0; nf < 2; ++nf)
          bb[nf] = *(const s16x8*)(Wb + b2off[nf][kf]);
#pragma unroll
        for (int mf = 0; mf < 4; ++mf)
#pragma unroll
          for (int nf = 0; nf < 2; ++nf)
            acc2[mf][nf] = __builtin_amdgcn_mfma_f32_16x16x32_bf16(a2[mf], bb[nf], acc2[mf][nf], 0, 0, 0);
      }
      asm volatile("s_waitcnt lgkmcnt(0)" ::: "memory");
      SB(); __builtin_amdgcn_s_barrier(); SB();

      if (s + 4 < 32) STAGE_W2(s + 4);
      if (kc == 0) {
        // T14: issue this nt's 32 residual X loads now (consumed at kc==3)
#pragma unroll
        for (int mf = 0; mf < 4; ++mf)
#pragma unroll
          for (int j = 0; j < 4; ++j) {
            int r = wm * 64 + mf * 16 + lq * 4 + j;
            const float* gp = X + (size_t)(row0 + r) * 1024 + nt * 128 + wn * 32 + lr;
            xres[mf][j][0] = async_ldf(gp);
            xres[mf][j][1] = async_ldf(gp + 16);
          }
      }

      if (kc < 3) {
        // trailing wait: retire W2(s+1); keep X + newer W2 in flight
        if (nt == 7)      { VMW(32); }
        else if (kc == 0) { VMW(34); }   // also drains prev nt's stores
        else              { VMW(38); }
        SB(); __builtin_amdgcn_s_barrier(); SB();
      } else {
        // retire this nt's X (and all older) before the epilogue
        if (nt == 7) { VMW(0); } else { VMW(6); }
        SB();
#pragma unroll
        for (int mf = 0; mf < 4; ++mf)
#pragma unroll
          for (int j = 0; j < 4; ++j) {
            int r = wm * 64 + mf * 16 + lq * 4 + j;
            size_t gb = (size_t)(row0 + r) * 1024 + nt * 128 + wn * 32;
#pragma unroll
            for (int nf = 0; nf < 2; ++nf)
              out[gb + nf * 16 + lr] =
                  acc2[mf][nf][j] * ugA[nt][nf] + ubA[nt][nf] * asv[mf][j] + xres[mf][j][nf];
          }
        if (nt < 7) { SB(); __builtin_amdgcn_s_barrier(); SB(); }
      }
    }
  }
}

extern "C" void kernel_launch(void* const* d_in, const int* in_sizes, int n_in,
                              void* d_out, int out_size, void* d_ws, size_t ws_size,
                              hipStream_t stream) {
  const float* hidden       = (const float*)d_in[0];
  const float* conditions   = (const float*)d_in[1];
  const float* down_project = (const float*)d_in[2];
  const float* down_gamma   = (const float*)d_in[3];
  const float* down_beta    = (const float*)d_in[4];
  const float* up_project   = (const float*)d_in[5];
  const float* up_gamma     = (const float*)d_in[6];
  const float* up_beta      = (const float*)d_in[7];
  float* out = (float*)d_out;
  char* ws = (char*)d_ws;

  prep_kernel<<<224, 256, 0, stream>>>(conditions, down_gamma, down_beta, up_gamma, up_beta,
                                       down_project, up_project, ws);
  fused_kernel<<<256, 512, 0, stream>>>(hidden, ws, out);
}

// Round 11
// 89.419 us; speedup vs baseline: 1.9294x; 1.0540x over previous
//
#include <hip/hip_runtime.h>
#include <hip/hip_bf16.h>

typedef __attribute__((ext_vector_type(4))) float f32x4;
typedef __attribute__((ext_vector_type(8))) short s16x8;
typedef __attribute__((ext_vector_type(8))) unsigned short u16x8;
typedef __attribute__((ext_vector_type(4))) unsigned int u32x4;

#define DEVFN static __device__ __forceinline__

DEVFN unsigned short f2bf(float f) {
  union { float f; unsigned int u; } v; v.f = f;
  unsigned int u = v.u;
  u += 0x7fffu + ((u >> 16) & 1u);   // RNE
  return (unsigned short)(u >> 16);
}

DEVFN unsigned int cvt_pk(float a, float b) {
  __hip_bfloat162 h = __float22bfloat162_rn(make_float2(a, b));
  union { __hip_bfloat162 h; unsigned int u; } v; v.h = h; return v.u;
}

DEVFN void gl_lds16(const void* g, void* l) {
  __builtin_amdgcn_global_load_lds((__attribute__((address_space(1))) void*)g,
                                   (__attribute__((address_space(3))) void*)l, 16, 0, 0);
}

#define SB() __builtin_amdgcn_sched_barrier(0)
#define VMW(n) asm volatile("s_waitcnt vmcnt(" #n ")" ::: "memory")
#define LGKM0() asm volatile("s_waitcnt lgkmcnt(0)" ::: "memory")
#define BAR() { SB(); __builtin_amdgcn_s_barrier(); SB(); }

// ws layout (bytes)
#define DG_OFF 0
#define DB_OFF 2048
#define UG_OFF 4096
#define UB_OFF 12288
#define W1_BYTE 81920        // [32 ks][256 n][32 k] bf16, 64B rows, g^=((n>>1)&3)  (512 KB)
#define W2_BYTE 606208       // [8 nt][4 kc][128 n][64 k] bf16, g^=(n&7)            (512 KB)

// ---------- prep: W1 (0..31) + W2 (32..63) + coef (64..223) ----------
__global__ void prep_kernel(const float* __restrict__ cond,
                            const float* __restrict__ dgm, const float* __restrict__ dbt,
                            const float* __restrict__ ugm, const float* __restrict__ ubt,
                            const float* __restrict__ Wd, const float* __restrict__ Wu,
                            char* __restrict__ ws) {
  __shared__ float lc[4096];
  __shared__ float red[2048];
  const int t = threadIdx.x;

  if (blockIdx.x < 32) {
    // W1 slice ks: [256 n][32 k] bf16; row n 64B; granule g at ((g ^ ((n>>1)&3))<<4)
    const int ks = blockIdx.x;
    const int n = t;
    const float* sp = Wd + (size_t)(ks * 32) * 256 + n;
    unsigned short tmp[32];
#pragma unroll
    for (int kk = 0; kk < 32; ++kk) tmp[kk] = f2bf(sp[(size_t)kk * 256]);
    char* dst = ws + W1_BYTE + (size_t)ks * 16384 + n * 64;
#pragma unroll
    for (int g = 0; g < 4; ++g) {
      u16x8 v;
#pragma unroll
      for (int e = 0; e < 8; ++e) v[e] = tmp[g * 8 + e];
      *(u16x8*)(dst + ((g ^ ((n >> 1) & 3)) << 4)) = v;
    }
    return;
  }
  if (blockIdx.x < 64) {
    // W2 chunk (nt,kc): [128 n][64 k] bf16, g^=(n&7) (round-6 exact)
    int b2 = blockIdx.x - 32;
    int ntile = b2 >> 2, kc = b2 & 3;
    const int n = t >> 1, kh = t & 1;
    const float* sp = Wu + (size_t)(kc * 64 + kh * 32) * 1024 + ntile * 128 + n;
    unsigned short tmp[32];
#pragma unroll
    for (int kk = 0; kk < 32; ++kk) tmp[kk] = f2bf(sp[(size_t)kk * 1024]);
    char* dst = ws + W2_BYTE + (size_t)(ntile * 4 + kc) * 16384 + n * 128;
#pragma unroll
    for (int gi = 0; gi < 4; ++gi) {
      u16x8 v;
#pragma unroll
      for (int e = 0; e < 8; ++e) v[e] = tmp[gi * 8 + e];
      int g = kh * 4 + gi;
      *(u16x8*)(dst + ((g ^ (n & 7)) << 4)) = v;
    }
    return;
  }

  float* coef = (float*)ws;
#pragma unroll
  for (int i = 0; i < 16; ++i) lc[t + i * 256] = cond[t + i * 256];
  __syncthreads();
  const int bid2 = blockIdx.x - 64;
  const int col = bid2 * 16 + (t & 15);
  const int ks = t >> 4;
  const float* src; int ncol, cl;
  if (col < 256)       { src = dgm; ncol = 256;  cl = col; }
  else if (col < 512)  { src = dbt; ncol = 256;  cl = col - 256; }
  else if (col < 1536) { src = ugm; ncol = 1024; cl = col - 512; }
  else                 { src = ubt; ncol = 1024; cl = col - 1536; }
  float acc[8] = {};
  for (int k = ks * 32; k < ks * 32 + 32; ++k) {
    float g = src[(size_t)k * ncol + cl];
#pragma unroll
    for (int b = 0; b < 8; ++b) acc[b] = fmaf(lc[b * 512 + k], g, acc[b]);
  }
#pragma unroll
  for (int b = 0; b < 8; ++b) red[(ks * 16 + (t & 15)) * 8 + b] = acc[b];
  __syncthreads();
  if (t < 128) {
    int c = t >> 3, b = t & 7;
    float s = 0.f;
#pragma unroll
    for (int k2 = 0; k2 < 16; ++k2) s += red[(k2 * 16 + c) * 8 + b];
    int colg = bid2 * 16 + c;
    float* dst; int ncol2, cl2;
    if (colg < 256)       { dst = coef + DG_OFF; ncol2 = 256;  cl2 = colg; }
    else if (colg < 512)  { dst = coef + DB_OFF; ncol2 = 256;  cl2 = colg - 256; }
    else if (colg < 1536) { dst = coef + UG_OFF; ncol2 = 1024; cl2 = colg - 512; }
    else                  { dst = coef + UB_OFF; ncol2 = 1024; cl2 = colg - 1536; }
    dst[b * ncol2 + cl2] = s;
  }
}

// ---------- fused kernel: BM=64, 512 blocks x 512 threads, 2 blocks/CU ----------
// LDS 80 KiB: act[4kc][64r][64k]bf16 @0 (32K) | X f32 dbuf @32K (2x16K) | W1 @64K (16K)
// Phase 2 reuses 32K..80K as W2 triple-buffer (3x16K).
__global__ __launch_bounds__(512, 4)
void fused_kernel(const float* __restrict__ X, char* __restrict__ ws,
                  float* __restrict__ out) {
  __shared__ char lds[81920];
  const int tid = threadIdx.x;
  const int lane = tid & 63, lr = lane & 15, lq = lane >> 4;
  const int wave = tid >> 6;
  const int wm = wave >> 2, wn = wave & 3;   // 2m x 4n

  const int raw = blockIdx.x;
  const int m = (raw & 7) * 64 + (raw >> 3);   // XCD-chunked, 512 % 8 == 0
  const int row0 = m << 6;
  const int b = m >> 6;

  const float* coef = (const float*)ws;
  const char* w1 = ws + W1_BYTE;
  const char* w2 = ws + W2_BYTE;

  // ===== phase 1: X @ Wd  (16 X-steps of K=64, each = 2 W-sub-steps of K=32) =====
  const int srow = tid >> 4, sg = tid & 15;
  const float* xsrc = X + (size_t)(row0 + srow) * 1024 + ((sg ^ (srow & 15)) << 2);

  int aoff[2][2][2];
#pragma unroll
  for (int mf = 0; mf < 2; ++mf)
#pragma unroll
    for (int h = 0; h < 2; ++h) {
      int r = wm * 32 + mf * 16 + lr;
      int g0 = h * 8 + lq * 2;
      aoff[mf][h][0] = r * 256 + ((g0 ^ (r & 15)) << 4);
      aoff[mf][h][1] = r * 256 + (((g0 + 1) ^ (r & 15)) << 4);
    }
  int boff[4];
#pragma unroll
  for (int nf = 0; nf < 4; ++nf) {
    int n = wn * 64 + nf * 16 + lr;
    boff[nf] = n * 64 + ((lq ^ ((n >> 1) & 3)) << 4);
  }

  f32x4 acc1[2][4] = {};
  float hacc[2] = {0.f, 0.f};

#define XB(i) (lds + 32768 + (i) * 16384)
#define W1B   (lds + 65536)
#define STAGE_X(t)                                                               \
  { char* xb = XB((t) & 1);                                                      \
    gl_lds16(xsrc + (size_t)(t) * 64, xb + tid * 16);                            \
    gl_lds16(xsrc + 32 * 1024 + (size_t)(t) * 64, xb + 8192 + tid * 16); }
#define STAGE_W1(ks)                                                             \
  { gl_lds16(w1 + (size_t)(ks) * 16384 + tid * 16, W1B + tid * 16);              \
    gl_lds16(w1 + (size_t)(ks) * 16384 + 8192 + tid * 16, W1B + 8192 + tid * 16); }

#define MFMA_SUB(Xc, h)                                                          \
  { s16x8 afr[2];                                                                \
    _Pragma("unroll")                                                            \
    for (int mf = 0; mf < 2; ++mf) {                                             \
      f32x4 fa0 = *(const f32x4*)((Xc) + aoff[mf][h][0]);                        \
      f32x4 fa1 = *(const f32x4*)((Xc) + aoff[mf][h][1]);                        \
      if (wn == 0)                                                               \
        hacc[mf] += fa0[0] + fa0[1] + fa0[2] + fa0[3] +                          \
                    fa1[0] + fa1[1] + fa1[2] + fa1[3];                           \
      union { u32x4 u; s16x8 s; } cv;                                            \
      cv.u[0] = cvt_pk(fa0[0], fa0[1]); cv.u[1] = cvt_pk(fa0[2], fa0[3]);        \
      cv.u[2] = cvt_pk(fa1[0], fa1[1]); cv.u[3] = cvt_pk(fa1[2], fa1[3]);        \
      afr[mf] = cv.s;                                                            \
    }                                                                            \
    s16x8 bfr[4];                                                                \
    _Pragma("unroll")                                                            \
    for (int nf = 0; nf < 4; ++nf) bfr[nf] = *(const s16x8*)(W1B + boff[nf]);    \
    _Pragma("unroll")                                                            \
    for (int mf = 0; mf < 2; ++mf)                                               \
      _Pragma("unroll")                                                          \
      for (int nf = 0; nf < 4; ++nf)                                             \
        acc1[mf][nf] = __builtin_amdgcn_mfma_f32_16x16x32_bf16(afr[mf], bfr[nf], \
                                                               acc1[mf][nf], 0, 0, 0); }

  STAGE_X(0); STAGE_X(1); STAGE_W1(0);
  VMW(0); BAR();

  for (int t = 0; t < 16; ++t) {
    const char* Xc = XB(t & 1);
    // ---- sub A: W slice 2t, X half 0 ----
    MFMA_SUB(Xc, 0);
    LGKM0(); BAR();
    STAGE_W1(2 * t + 1);
    VMW(0); BAR();
    // ---- sub B: W slice 2t+1, X half 1 ----
    MFMA_SUB(Xc, 1);
    LGKM0(); BAR();
    if (t < 15) STAGE_W1(2 * t + 2);
    if (t < 14) { STAGE_X(t + 2); VMW(2); }
    else        { VMW(0); }
    BAR();
  }

  // ===== phase-1 epilogue: hsum, modulate+relu -> act LDS, asum =====
  float* hsumb = (float*)(lds + 32768);          // 64 f32
  float* asp   = (float*)(lds + 33024);          // [4 wn][64 r] f32
  if (wn == 0) {
#pragma unroll
    for (int mf = 0; mf < 2; ++mf) {
      float s = hacc[mf];
      s += __shfl_xor(s, 16); s += __shfl_xor(s, 32);
      if (lq == 0) hsumb[wm * 32 + mf * 16 + lr] = s;
    }
  }
  __syncthreads();

  float dgv[4], dbv[4];
#pragma unroll
  for (int nf = 0; nf < 4; ++nf) {
    int h = wn * 64 + nf * 16 + lr;
    dgv[nf] = coef[DG_OFF + b * 256 + h];
    dbv[nf] = coef[DB_OFF + b * 256 + h];
  }

  float asacc[2][4] = {};
#pragma unroll
  for (int nf = 0; nf < 4; ++nf) {
    int g = nf * 2 + (lr >> 3);
    char* nbase = lds + wn * 8192 + (lr & 7) * 2;   // act chunk kc = wn (8 KB chunks)
    float dg_ = dgv[nf], db_ = dbv[nf];
#pragma unroll
    for (int mf = 0; mf < 2; ++mf) {
#pragma unroll
      for (int j = 0; j < 4; ++j) {
        int r = wm * 32 + mf * 16 + lq * 4 + j;
        float v = acc1[mf][nf][j] * dg_ + db_ * hsumb[r];
        v = fmaxf(v, 0.f);
        asacc[mf][j] += v;
        *(unsigned short*)(nbase + r * 128 + ((g ^ (r & 7)) << 4)) = f2bf(v);
      }
    }
  }
#pragma unroll
  for (int mf = 0; mf < 2; ++mf)
#pragma unroll
    for (int j = 0; j < 4; ++j) {
      float s = asacc[mf][j];
      s += __shfl_xor(s, 1); s += __shfl_xor(s, 2); s += __shfl_xor(s, 4); s += __shfl_xor(s, 8);
      if (lr == 0) asp[wn * 64 + wm * 32 + mf * 16 + lq * 4 + j] = s;
    }
  __syncthreads();

  float asv[2][4];
#pragma unroll
  for (int mf = 0; mf < 2; ++mf)
#pragma unroll
    for (int j = 0; j < 4; ++j) {
      int r = wm * 32 + mf * 16 + lq * 4 + j;
      asv[mf][j] = asp[r] + asp[64 + r] + asp[128 + r] + asp[192 + r];
    }
  __syncthreads();   // asp consumed before W2 staging overwrites 32768..

  // ===== phase 2: act @ Wu, 32 steps (8 nt x 4 kc), W2 triple-buffer =====
  int a2off[2][2], b2off[2][2];
#pragma unroll
  for (int mf = 0; mf < 2; ++mf)
#pragma unroll
    for (int kf = 0; kf < 2; ++kf) {
      int r = wm * 32 + mf * 16 + lr;
      a2off[mf][kf] = r * 128 + (((kf * 4 + lq) ^ (r & 7)) << 4);
    }
#pragma unroll
  for (int nf = 0; nf < 2; ++nf)
#pragma unroll
    for (int kf = 0; kf < 2; ++kf) {
      int nl = wn * 32 + nf * 16 + lr;
      b2off[nf][kf] = nl * 128 + (((kf * 4 + lq) ^ (nl & 7)) << 4);
    }

#define W2B(s) (lds + 32768 + ((s) % 3) * 16384)
#define STAGE_W2(s)                                                              \
  { gl_lds16(w2 + (size_t)(s) * 16384 + tid * 16, W2B(s) + tid * 16);            \
    gl_lds16(w2 + (size_t)(s) * 16384 + 8192 + tid * 16,                         \
             W2B(s) + 8192 + tid * 16); }

  STAGE_W2(0); STAGE_W2(1);
  VMW(2); BAR();

  float ugv[2], ubv[2];
#pragma unroll
  for (int s = 0; s < 32; ++s) {
    const int nt = s >> 2, kc = s & 3;
    f32x4 acc2[2][2];
    if (kc == 0) {
#pragma unroll
      for (int mf = 0; mf < 2; ++mf)
#pragma unroll
        for (int nf = 0; nf < 2; ++nf) acc2[mf][nf] = (f32x4){0.f, 0.f, 0.f, 0.f};
    }
    static f32x4 dummy;  // (unused; keeps acc2 in scope across kc via unroll SSA)
    const char* Wb = W2B(s);
#pragma unroll
    for (int kf = 0; kf < 2; ++kf) {
      s16x8 a2[2], bb[2];
#pragma unroll
      for (int mf = 0; mf < 2; ++mf)
        a2[mf] = *(const s16x8*)(lds + kc * 8192 + a2off[mf][kf]);
#pragma unroll
      for (int nf = 0; nf < 2; ++nf)
        bb[nf] = *(const s16x8*)(Wb + b2off[nf][kf]);
#pragma unroll
      for (int mf = 0; mf < 2; ++mf)
#pragma unroll
        for (int nf = 0; nf < 2; ++nf)
          acc2[mf][nf] = __builtin_amdgcn_mfma_f32_16x16x32_bf16(a2[mf], bb[nf], acc2[mf][nf], 0, 0, 0);
    }
    LGKM0(); BAR();

    if (kc == 0) {
      // per-nt modulation coefs (older than the W2 stage below -> counting safe)
#pragma unroll
      for (int nf = 0; nf < 2; ++nf) {
        int d = nt * 128 + wn * 32 + nf * 16 + lr;
        ugv[nf] = coef[UG_OFF + b * 1024 + d];
        ubv[nf] = coef[UB_OFF + b * 1024 + d];
      }
    }
    if (s + 2 < 32) STAGE_W2(s + 2);
    if (kc == 3) {
      // epilogue for nt: modulation + asum + residual; 128B/wave segments
#pragma unroll
      for (int mf = 0; mf < 2; ++mf)
#pragma unroll
        for (int j = 0; j < 4; ++j) {
          int r = wm * 32 + mf * 16 + lq * 4 + j;
          size_t gbase = (size_t)(row0 + r) * 1024 + nt * 128 + wn * 32;
#pragma unroll
          for (int nf = 0; nf < 2; ++nf) {
            size_t gi = gbase + nf * 16 + lr;
            out[gi] = acc2[mf][nf][j] * ugv[nf] + ubv[nf] * asv[mf][j] + X[gi];
          }
        }
    }
    if (s < 31) {
      if (s + 2 >= 32)  { VMW(0); }     // s == 30: wait final W2 chunk
      else if (kc == 3) { VMW(16); }    // stores may stay in flight; W2 already drained
      else              { VMW(2); }     // keep newest stage (s+2) in flight
      BAR();
    }
    (void)dummy;
  }
}

extern "C" void kernel_launch(void* const* d_in, const int* in_sizes, int n_in,
                              void* d_out, int out_size, void* d_ws, size_t ws_size,
                              hipStream_t stream) {
  const float* hidden       = (const float*)d_in[0];
  const float* conditions   = (const float*)d_in[1];
  const float* down_project = (const float*)d_in[2];
  const float* down_gamma   = (const float*)d_in[3];
  const float* down_beta    = (const float*)d_in[4];
  const float* up_project   = (const float*)d_in[5];
  const float* up_gamma     = (const float*)d_in[6];
  const float* up_beta      = (const float*)d_in[7];
  float* out = (float*)d_out;
  char* ws = (char*)d_ws;

  prep_kernel<<<224, 256, 0, stream>>>(conditions, down_gamma, down_beta, up_gamma, up_beta,
                                       down_project, up_project, ws);
  fused_kernel<<<512, 512, 0, stream>>>(hidden, ws, out);
}